// Round 6
// baseline (155.163 us; speedup 1.0000x reference)
//
#include <hip/hip_runtime.h>
#include <hip/hip_bf16.h>
#include <math.h>

typedef float f32x4 __attribute__((ext_vector_type(4)));
typedef __bf16 bf16_t;
typedef bf16_t bf16x8 __attribute__((ext_vector_type(8)));
typedef bf16_t bf16x4 __attribute__((ext_vector_type(4)));

// async global->LDS, 16B per lane; LDS dest = wave-uniform base + lane*16
__device__ __forceinline__ void gload_lds16(const bf16_t* g, bf16_t* l) {
    __builtin_amdgcn_global_load_lds(
        (const __attribute__((address_space(1))) unsigned int*)g,
        (__attribute__((address_space(3))) unsigned int*)l, 16, 0, 0);
}

template<int N_IMM>
__device__ __forceinline__ void wait_vmcnt() {
    if constexpr (N_IMM == 0) asm volatile("s_waitcnt vmcnt(0)" ::: "memory");
    else if constexpr (N_IMM == 2) asm volatile("s_waitcnt vmcnt(2)" ::: "memory");
    else if constexpr (N_IMM == 3) asm volatile("s_waitcnt vmcnt(3)" ::: "memory");
    else if constexpr (N_IMM == 4) asm volatile("s_waitcnt vmcnt(4)" ::: "memory");
    else static_assert(N_IMM == 0, "unsupported vmcnt");
}

// ---------------- fused fp32 -> bf16 conversion for 3 arrays ----------------
__global__ __launch_bounds__(256) void cvt3(const float* __restrict__ a, bf16_t* __restrict__ ao, int na4,
                                            const float* __restrict__ b, bf16_t* __restrict__ bo, int nb4,
                                            const float* __restrict__ c, bf16_t* __restrict__ co, int nc4) {
    int q = blockIdx.x * 256 + threadIdx.x;   // quad index
    const float* src; bf16_t* dst;
    if (q < na4)            { src = a + (size_t)q * 4;              dst = ao + (size_t)q * 4; }
    else if (q < na4 + nb4) { int r = q - na4; src = b + (size_t)r * 4; dst = bo + (size_t)r * 4; }
    else if (q < na4 + nb4 + nc4) { int r = q - na4 - nb4; src = c + (size_t)r * 4; dst = co + (size_t)r * 4; }
    else return;
    float4 v = *reinterpret_cast<const float4*>(src);
    bf16x4 o;
    o[0] = (bf16_t)v.x; o[1] = (bf16_t)v.y; o[2] = (bf16_t)v.z; o[3] = (bf16_t)v.w;
    *reinterpret_cast<bf16x4*>(dst) = o;
}

// ---------------- GEMM1: 8-wave 128x256 tile, BK=64, 2-phase minimum template ----------------
// T3-min (m248-style): per K-tile: STAGE(next buf) -> ds_read+MFMA(cur) ->
// vmcnt(0)+s_barrier. Stage issued BEFORE compute so HBM latency hides under
// 32 MFMA/wave. One barrier per tile. Linear LDS, source-preswizzled
// (slot ^ (row&7) over 8x16B slots per 128B row); same XOR on ds_read.
// Grid 256 blocks (1/CU), 512 threads (8 waves, 2x4 of 64x64).
// EPI0 epilogue: softplus x2 / gelu x2 by col>>10, store bf16.
__global__ __launch_bounds__(512) void gemm8(const bf16_t* __restrict__ A,
                                             const bf16_t* __restrict__ B,
                                             const float* __restrict__ bias,
                                             bf16_t* __restrict__ Cout,
                                             int M, int N, int K) {
    __shared__ bf16_t As[2][128 * 64];   // 32KB
    __shared__ bf16_t Bs[2][256 * 64];   // 64KB
    const int tid = threadIdx.x;
    const int lane = tid & 63;
    const int w = tid >> 6;              // 0..7
    const int wr = w >> 2, wc = w & 3;   // 2 x 4 waves

    // bijective XCD swizzle: 8 chunks (2m x 4n tile-chunks of 8x4 tiles each)
    // per-XCD footprint: A 8*128 rows (2MB) + B 4*256 rows (2MB) = 4MB = L2
    const int c = blockIdx.x & 7;
    const int pp = blockIdx.x >> 3;      // 0..31
    const int mt = (c & 1) * 8 + (pp & 7);
    const int nt = (c >> 1) * 4 + (pp >> 3);
    const int m0 = mt * 128, n0 = nt * 256;

    const int l15 = lane & 15, lg = lane >> 4;
    const int srow = lane >> 3;          // 0..7 rows per 1KB segment
    const int slot = lane & 7;           // 16B slot within 128B row

    f32x4 acc[4][4] = {};
    const int TNUM = K / 64;             // 16

    auto stage = [&](int buf, int k0) {
#pragma unroll
        for (int t = 0; t < 2; ++t) {    // A: 16 segments of 8 rows
            int s = w + t * 8;
            int row = s * 8 + srow;
            int cg = slot ^ (row & 7);
            gload_lds16(&A[(size_t)(m0 + row) * K + k0 + cg * 8], &As[buf][s * 512]);
        }
#pragma unroll
        for (int t = 0; t < 4; ++t) {    // B: 32 segments of 8 rows
            int s = w + t * 8;
            int row = s * 8 + srow;
            int cg = slot ^ (row & 7);
            gload_lds16(&B[(size_t)(n0 + row) * K + k0 + cg * 8], &Bs[buf][s * 512]);
        }
    };

    stage(0, 0);
    wait_vmcnt<0>();
    __builtin_amdgcn_s_barrier();
    __builtin_amdgcn_sched_barrier(0);

    int cur = 0;
    for (int t = 0; t < TNUM; ++t) {
        if (t + 1 < TNUM) stage(cur ^ 1, (t + 1) * 64);   // in flight across compute

        const bf16_t* Ac = As[cur];
        const bf16_t* Bc = Bs[cur];
#pragma unroll
        for (int kk = 0; kk < 2; ++kk) {
            bf16x8 af[4], bfr[4];
#pragma unroll
            for (int i = 0; i < 4; ++i) {
                int ar = wr * 64 + i * 16 + l15;
                int ch = (kk * 4 + lg) ^ (ar & 7);
                af[i] = *(const bf16x8*)(&Ac[ar * 64 + ch * 8]);
            }
#pragma unroll
            for (int j = 0; j < 4; ++j) {
                int br = wc * 64 + j * 16 + l15;
                int ch = (kk * 4 + lg) ^ (br & 7);
                bfr[j] = *(const bf16x8*)(&Bc[br * 64 + ch * 8]);
            }
#pragma unroll
            for (int i = 0; i < 4; ++i)
#pragma unroll
                for (int j = 0; j < 4; ++j)
                    acc[i][j] = __builtin_amdgcn_mfma_f32_16x16x32_bf16(af[i], bfr[j], acc[i][j], 0, 0, 0);
        }
        __builtin_amdgcn_sched_barrier(0);
        wait_vmcnt<0>();                 // next tile fully landed
        __builtin_amdgcn_s_barrier();    // all waves done reading cur + staging
        __builtin_amdgcn_sched_barrier(0);
        cur ^= 1;
    }

    // epilogue: C/D layout col = lane&15, row = (lane>>4)*4 + reg
#pragma unroll
    for (int i = 0; i < 4; ++i) {
        int gm_base = m0 + wr * 64 + i * 16 + lg * 4;
#pragma unroll
        for (int j = 0; j < 4; ++j) {
            int gn = n0 + wc * 64 + j * 16 + l15;
            float bv = bias[gn];
#pragma unroll
            for (int r = 0; r < 4; ++r) {
                int gm = gm_base + r;
                float v = acc[i][j][r] + bv;
                float a;
                if ((gn >> 10) < 2) {
                    a = fmaxf(v, 0.f) + log1pf(expf(-fabsf(v)));           // softplus
                } else {
                    a = 0.5f * v * (1.f + erff(v * 0.70710678118654752f)); // exact gelu
                }
                Cout[(size_t)gm * N + gn] = (bf16_t)a;
            }
        }
    }
}

// ---------------- GEMM2: R3-proven 4-wave 2-buffer loop (best measured) ----------------
template<int BM, int BN, int MR, int NR>
__global__ __launch_bounds__(256) void gemm_bt(const bf16_t* __restrict__ A,
                                               const bf16_t* __restrict__ B,
                                               const float* __restrict__ bias,
                                               float* __restrict__ Cout,
                                               int M, int N, int K) {
    constexpr int WCOLS = BN / (NR * 16);
    constexpr int WROWS = BM / (MR * 16);
    static_assert(WROWS * WCOLS == 4, "4 waves");
    constexpr int ASEG = BM / 64, BSEG = BN / 64;
    constexpr int LOADS = ASEG + BSEG;
    __shared__ bf16_t As[2][BM * 32];
    __shared__ bf16_t Bs[2][BN * 32];
    const int tid = threadIdx.x;
    const int lane = tid & 63;
    const int w = tid >> 6;
    const int wr = w / WCOLS, wc = w % WCOLS;

    // bijective XCD swizzle: 8 chunks of 8 x chunkN tiles
    const int NTM = M / BM, NTN = N / BN;
    const int CHM = NTM >> 3;
    const int chunkN = (NTN * CHM) >> 3;
    const int c = blockIdx.x & 7;
    const int pp = blockIdx.x >> 3;
    const int mt = (c % CHM) * 8 + (pp & 7);
    const int nt = (c / CHM) * chunkN + (pp >> 3);
    const int m0 = mt * BM, n0 = nt * BN;

    const int l15 = lane & 15, lg = lane >> 4;
    const int srow = lane >> 2, pos = lane & 3;

    f32x4 acc[MR][NR] = {};
    const int TNUM = K / 32;

    auto stage = [&](int buf, int k0) {
#pragma unroll
        for (int t = 0; t < ASEG; ++t) {
            int s = w + t * 4;
            int row = s * 16 + srow;
            int ch = pos ^ ((row >> 1) & 3);
            gload_lds16(&A[(size_t)(m0 + row) * K + k0 + ch * 8], &As[buf][s * 512]);
        }
#pragma unroll
        for (int t = 0; t < BSEG; ++t) {
            int s = w + t * 4;
            int row = s * 16 + srow;
            int ch = pos ^ ((row >> 1) & 3);
            gload_lds16(&B[(size_t)(n0 + row) * K + k0 + ch * 8], &Bs[buf][s * 512]);
        }
    };

    stage(0, 0);
    int cur = 0;
    for (int t = 0; t < TNUM; ++t) {
        if (t + 1 < TNUM) {
            stage(cur ^ 1, (t + 1) * 32);
            wait_vmcnt<LOADS>();
        } else {
            wait_vmcnt<0>();
        }
        __builtin_amdgcn_s_barrier();
        __builtin_amdgcn_sched_barrier(0);

        const bf16_t* Ac = As[cur];
        const bf16_t* Bc = Bs[cur];
        bf16x8 af[MR], bfr[NR];
#pragma unroll
        for (int i = 0; i < MR; ++i) {
            int ar = wr * MR * 16 + i * 16 + l15;
            af[i] = *(const bf16x8*)(&Ac[ar * 32 + (lg ^ ((ar >> 1) & 3)) * 8]);
        }
#pragma unroll
        for (int j = 0; j < NR; ++j) {
            int br = wc * NR * 16 + j * 16 + l15;
            bfr[j] = *(const bf16x8*)(&Bc[br * 32 + (lg ^ ((br >> 1) & 3)) * 8]);
        }
#pragma unroll
        for (int i = 0; i < MR; ++i)
#pragma unroll
            for (int j = 0; j < NR; ++j)
                acc[i][j] = __builtin_amdgcn_mfma_f32_16x16x32_bf16(af[i], bfr[j], acc[i][j], 0, 0, 0);
        __builtin_amdgcn_sched_barrier(0);
        __builtin_amdgcn_s_barrier();
        cur ^= 1;
    }

#pragma unroll
    for (int i = 0; i < MR; ++i) {
        int gm_base = m0 + wr * MR * 16 + i * 16 + lg * 4;
#pragma unroll
        for (int j = 0; j < NR; ++j) {
            int gn = n0 + wc * NR * 16 + j * 16 + l15;
            float bv = bias[gn];
#pragma unroll
            for (int r = 0; r < 4; ++r) {
                int gm = gm_base + r;
                Cout[(size_t)gm * N + gn] = acc[i][j][r] + bv;
            }
        }
    }
}

// ---------------- A = K^T Q partials per (b,h), 8 token chunks ----------------
// qkvg layout: [(b*1024+n)*4096 + s*1024 + h*64 + e], s in {q,k,v,g}
__global__ __launch_bounds__(256) void attn_A(const bf16_t* __restrict__ qkvg,
                                              float* __restrict__ Apart) {
    const int bh = blockIdx.x;           // 0..31
    const int p = blockIdx.y;            // 0..7
    const int b = bh >> 4, h = bh & 15;
    const int tid = threadIdx.x;
    __shared__ float ks[32][64];
    __shared__ float qs[32][64];
    float acc[4][4] = {};
    const int dg = tid >> 4, eg = tid & 15;
    const int stok = tid >> 3, se0 = (tid & 7) * 8;
    const size_t base = ((size_t)b * 1024) * 4096 + (size_t)h * 64;

    for (int t0 = p * 128; t0 < p * 128 + 128; t0 += 32) {
        __syncthreads();
        size_t rowb = base + (size_t)(t0 + stok) * 4096;
        bf16x8 qv8 = *(const bf16x8*)(&qkvg[rowb + se0]);
        bf16x8 kv8 = *(const bf16x8*)(&qkvg[rowb + 1024 + se0]);
#pragma unroll
        for (int jj = 0; jj < 8; ++jj) {
            qs[stok][se0 + jj] = (float)qv8[jj];
            ks[stok][se0 + jj] = (float)kv8[jj];
        }
        __syncthreads();
#pragma unroll 8
        for (int tt = 0; tt < 32; ++tt) {
            f32x4 kv = *(const f32x4*)(&ks[tt][dg * 4]);
            f32x4 qv = *(const f32x4*)(&qs[tt][eg * 4]);
#pragma unroll
            for (int i = 0; i < 4; ++i)
#pragma unroll
                for (int j = 0; j < 4; ++j) acc[i][j] += kv[i] * qv[j];
        }
    }
    float* dst = Apart + ((size_t)p * 32 + bh) * 4096;
#pragma unroll
    for (int i = 0; i < 4; ++i)
#pragma unroll
        for (int j = 0; j < 4; ++j)
            dst[(dg * 4 + i) * 64 + eg * 4 + j] = acc[i][j];
}

// ---------------- reduce partials -> A, compute z ----------------
__global__ __launch_bounds__(256) void reduce_A_z(const float* __restrict__ Apart,
                                                  float* __restrict__ A,
                                                  float* __restrict__ z) {
    const int bh = blockIdx.x;
    const int tid = threadIdx.x;
    __shared__ float As[4096];
    for (int i0 = tid * 4; i0 < 4096; i0 += 1024) {
        f32x4 s = {};
#pragma unroll
        for (int p = 0; p < 8; ++p) {
            f32x4 v = *(const f32x4*)(&Apart[((size_t)p * 32 + bh) * 4096 + i0]);
            s += v;
        }
        *(f32x4*)(&As[i0]) = s;
        *(f32x4*)(&A[(size_t)bh * 4096 + i0]) = s;
    }
    __syncthreads();
    if (tid < 64) {
        float s = 0.f;
#pragma unroll 8
        for (int d = 0; d < 64; ++d) s += As[d * 64 + tid];
        z[bh * 64 + tid] = 1.0f / (s * 0.125f + 1024.0f);
    }
}

// ---------------- Y = ((SCALE*V@A + V) * z * g), scrambled-reshaped, bf16 ----------------
__global__ __launch_bounds__(256) void out_Y(const bf16_t* __restrict__ qkvg,
                                             const float* __restrict__ A,
                                             const float* __restrict__ z,
                                             bf16_t* __restrict__ Y) {
    const int bh = blockIdx.x;
    const int b = bh >> 4, h = bh & 15;
    const int chunk = blockIdx.y;        // 0..15 -> 64 tokens
    const int tid = threadIdx.x;
    __shared__ float As[64][64];         // A[d][e]
    __shared__ float vs[32][64];
    __shared__ float zs[64];
    for (int i = tid; i < 4096; i += 256) As[i >> 6][i & 63] = A[(size_t)bh * 4096 + i];
    if (tid < 64) zs[tid] = z[bh * 64 + tid];
    const size_t base = ((size_t)b * 1024) * 4096 + (size_t)h * 64;
    const int e = tid & 63, trow = tid >> 6;
    const int stok = tid >> 3, se0 = (tid & 7) * 8;

    for (int t0 = chunk * 64; t0 < chunk * 64 + 64; t0 += 32) {
        __syncthreads();
        bf16x8 vv8 = *(const bf16x8*)(&qkvg[base + (size_t)(t0 + stok) * 4096 + 2048 + se0]);
#pragma unroll
        for (int jj = 0; jj < 8; ++jj) vs[stok][se0 + jj] = (float)vv8[jj];
        __syncthreads();
#pragma unroll
        for (int kk = 0; kk < 8; ++kk) {
            int ml = trow * 8 + kk;
            int m = t0 + ml;
            float s = 0.f;
#pragma unroll 8
            for (int d = 0; d < 64; ++d) s += vs[ml][d] * As[d][e];
            float g = (float)qkvg[base + (size_t)m * 4096 + 3072 + e];
            float o = (s * 0.125f + vs[ml][e]) * zs[e] * g;
            Y[((size_t)b * 1024 + h * 64 + (m >> 4)) * 1024 + ((m & 15) << 6) + e] = (bf16_t)o;
        }
    }
}

extern "C" void kernel_launch(void* const* d_in, const int* in_sizes, int n_in,
                              void* d_out, int out_size, void* d_ws, size_t ws_size,
                              hipStream_t stream) {
    const float* x      = (const float*)d_in[0];
    const float* w_qkvg = (const float*)d_in[1];
    const float* b_qkvg = (const float*)d_in[2];
    const float* w_proj = (const float*)d_in[3];
    const float* b_proj = (const float*)d_in[4];

    char* p = (char*)d_ws;
    bf16_t* xb    = (bf16_t*)p; p += (size_t)2048 * 1024 * 2;
    bf16_t* w1b   = (bf16_t*)p; p += (size_t)4096 * 1024 * 2;
    bf16_t* w2b   = (bf16_t*)p; p += (size_t)1024 * 1024 * 2;
    bf16_t* qkvg  = (bf16_t*)p; p += (size_t)2048 * 4096 * 2;
    float*  Apart = (float*)p;  p += (size_t)8 * 32 * 4096 * 4;
    float*  Afull = (float*)p;  p += (size_t)32 * 4096 * 4;
    float*  zbuf  = (float*)p;  p += (size_t)32 * 64 * 4;
    bf16_t* Ybuf  = (bf16_t*)p; p += (size_t)2048 * 1024 * 2;

    // quad counts: x 524288, w_qkvg 1048576, w_proj 262144 -> 7168 blocks
    cvt3<<<7168, 256, 0, stream>>>(x, xb, 524288, w_qkvg, w1b, 1048576, w_proj, w2b, 262144);

    // GEMM1: 2048x4096x1024, 128x256 tiles -> 256 blocks (1/CU, 96KB LDS, 8 waves)
    gemm8<<<256, 512, 0, stream>>>(xb, w1b, b_qkvg, qkvg, 2048, 4096, 1024);
    attn_A<<<dim3(32, 8), 256, 0, stream>>>(qkvg, Apart);
    reduce_A_z<<<32, 256, 0, stream>>>(Apart, Afull, zbuf);
    out_Y<<<dim3(32, 16), 256, 0, stream>>>(qkvg, Afull, zbuf, Ybuf);
    // GEMM2: 2048x1024x1024, 64x64 tiles -> 512 blocks (R3-proven loop)
    gemm_bt<64, 64, 2, 2><<<512, 256, 0, stream>>>(Ybuf, w2b, b_proj, (float*)d_out, 2048, 1024, 1024);
}

// Round 7
// 131.330 us; speedup vs baseline: 1.1815x; 1.1815x over previous
//
#include <hip/hip_runtime.h>
#include <hip/hip_bf16.h>
#include <math.h>

typedef float f32x4 __attribute__((ext_vector_type(4)));
typedef __bf16 bf16_t;
typedef bf16_t bf16x8 __attribute__((ext_vector_type(8)));
typedef bf16_t bf16x4 __attribute__((ext_vector_type(4)));

// async global->LDS, 16B per lane; LDS dest = wave-uniform base + lane*16
__device__ __forceinline__ void gload_lds16(const bf16_t* g, bf16_t* l) {
    __builtin_amdgcn_global_load_lds(
        (const __attribute__((address_space(1))) unsigned int*)g,
        (__attribute__((address_space(3))) unsigned int*)l, 16, 0, 0);
}

template<int N_IMM>
__device__ __forceinline__ void wait_vmcnt() {
    if constexpr (N_IMM == 0) asm volatile("s_waitcnt vmcnt(0)" ::: "memory");
    else if constexpr (N_IMM == 2) asm volatile("s_waitcnt vmcnt(2)" ::: "memory");
    else if constexpr (N_IMM == 3) asm volatile("s_waitcnt vmcnt(3)" ::: "memory");
    else if constexpr (N_IMM == 4) asm volatile("s_waitcnt vmcnt(4)" ::: "memory");
    else static_assert(N_IMM == 0, "unsupported vmcnt");
}

// ---------------- fused fp32 -> bf16 conversion for 3 arrays ----------------
__global__ __launch_bounds__(256) void cvt3(const float* __restrict__ a, bf16_t* __restrict__ ao, int na4,
                                            const float* __restrict__ b, bf16_t* __restrict__ bo, int nb4,
                                            const float* __restrict__ c, bf16_t* __restrict__ co, int nc4) {
    int q = blockIdx.x * 256 + threadIdx.x;   // quad index
    const float* src; bf16_t* dst;
    if (q < na4)            { src = a + (size_t)q * 4;              dst = ao + (size_t)q * 4; }
    else if (q < na4 + nb4) { int r = q - na4; src = b + (size_t)r * 4; dst = bo + (size_t)r * 4; }
    else if (q < na4 + nb4 + nc4) { int r = q - na4 - nb4; src = c + (size_t)r * 4; dst = co + (size_t)r * 4; }
    else return;
    float4 v = *reinterpret_cast<const float4*>(src);
    bf16x4 o;
    o[0] = (bf16_t)v.x; o[1] = (bf16_t)v.y; o[2] = (bf16_t)v.z; o[3] = (bf16_t)v.w;
    *reinterpret_cast<bf16x4*>(dst) = o;
}

// ---------------- bf16 GEMM: C = A @ B^T (+bias, epilogue), R3-proven loop ----------------
// 2-buffer counted-vmcnt pipeline (best measured config, ~900 TF at the
// 2048x1024x1024 / 64x64 / 512-block shape as GEMM2 in R3-R6).
// Staging linear LDS, source-preswizzled (ch = pos ^ ((row>>1)&3));
// swizzled ds_read_b128 -> 0 bank conflicts (verified R2).
// Bijective XCD chunk swizzle -> ~1MB A + ~1MB B slice per XCD.
// EPI 0: softplus, store bf16.  EPI 1: exact gelu, store bf16.  EPI 2: plain, store fp32.
// ldc: row stride of Cout (sub-GEMMs write strided into the 4096-wide qkvg).
template<int BM, int BN, int MR, int NR, int EPI>
__global__ __launch_bounds__(256) void gemm_bt(const bf16_t* __restrict__ A,
                                               const bf16_t* __restrict__ B,
                                               const float* __restrict__ bias,
                                               void* __restrict__ Cout,
                                               int M, int N, int K, int ldc) {
    constexpr int WCOLS = BN / (NR * 16);
    constexpr int WROWS = BM / (MR * 16);
    static_assert(WROWS * WCOLS == 4, "4 waves");
    constexpr int ASEG = BM / 64, BSEG = BN / 64;
    constexpr int LOADS = ASEG + BSEG;
    __shared__ bf16_t As[2][BM * 32];
    __shared__ bf16_t Bs[2][BN * 32];
    const int tid = threadIdx.x;
    const int lane = tid & 63;
    const int w = tid >> 6;
    const int wr = w / WCOLS, wc = w % WCOLS;

    // bijective XCD swizzle: 8 chunks of 8 x chunkN tiles
    const int NTM = M / BM, NTN = N / BN;
    const int CHM = NTM >> 3;
    const int chunkN = (NTN * CHM) >> 3;
    const int c = blockIdx.x & 7;
    const int pp = blockIdx.x >> 3;
    const int mt = (c % CHM) * 8 + (pp & 7);
    const int nt = (c / CHM) * chunkN + (pp >> 3);
    const int m0 = mt * BM, n0 = nt * BN;

    const int l15 = lane & 15, lg = lane >> 4;
    const int srow = lane >> 2, pos = lane & 3;

    f32x4 acc[MR][NR] = {};
    const int TNUM = K / 32;

    auto stage = [&](int buf, int k0) {
#pragma unroll
        for (int t = 0; t < ASEG; ++t) {
            int s = w + t * 4;
            int row = s * 16 + srow;
            int ch = pos ^ ((row >> 1) & 3);
            gload_lds16(&A[(size_t)(m0 + row) * K + k0 + ch * 8], &As[buf][s * 512]);
        }
#pragma unroll
        for (int t = 0; t < BSEG; ++t) {
            int s = w + t * 4;
            int row = s * 16 + srow;
            int ch = pos ^ ((row >> 1) & 3);
            gload_lds16(&B[(size_t)(n0 + row) * K + k0 + ch * 8], &Bs[buf][s * 512]);
        }
    };

    stage(0, 0);
    int cur = 0;
    for (int t = 0; t < TNUM; ++t) {
        if (t + 1 < TNUM) {
            stage(cur ^ 1, (t + 1) * 32);   // next tile in flight across compute
            wait_vmcnt<LOADS>();            // current tile landed
        } else {
            wait_vmcnt<0>();
        }
        __builtin_amdgcn_s_barrier();
        __builtin_amdgcn_sched_barrier(0);

        const bf16_t* Ac = As[cur];
        const bf16_t* Bc = Bs[cur];
        bf16x8 af[MR], bfr[NR];
#pragma unroll
        for (int i = 0; i < MR; ++i) {
            int ar = wr * MR * 16 + i * 16 + l15;
            af[i] = *(const bf16x8*)(&Ac[ar * 32 + (lg ^ ((ar >> 1) & 3)) * 8]);
        }
#pragma unroll
        for (int j = 0; j < NR; ++j) {
            int br = wc * NR * 16 + j * 16 + l15;
            bfr[j] = *(const bf16x8*)(&Bc[br * 32 + (lg ^ ((br >> 1) & 3)) * 8]);
        }
#pragma unroll
        for (int i = 0; i < MR; ++i)
#pragma unroll
            for (int j = 0; j < NR; ++j)
                acc[i][j] = __builtin_amdgcn_mfma_f32_16x16x32_bf16(af[i], bfr[j], acc[i][j], 0, 0, 0);
        __builtin_amdgcn_sched_barrier(0);
        __builtin_amdgcn_s_barrier();       // all reads of buf cur done
        cur ^= 1;
    }

    // epilogue: C/D layout col = lane&15, row = (lane>>4)*4 + reg
#pragma unroll
    for (int i = 0; i < MR; ++i) {
        int gm_base = m0 + wr * MR * 16 + i * 16 + lg * 4;
#pragma unroll
        for (int j = 0; j < NR; ++j) {
            int gn = n0 + wc * NR * 16 + j * 16 + l15;
            float bv = bias[gn];
#pragma unroll
            for (int r = 0; r < 4; ++r) {
                int gm = gm_base + r;
                float v = acc[i][j][r] + bv;
                if (EPI == 0) {
                    float a = fmaxf(v, 0.f) + log1pf(expf(-fabsf(v)));          // softplus
                    ((bf16_t*)Cout)[(size_t)gm * ldc + gn] = (bf16_t)a;
                } else if (EPI == 1) {
                    float a = 0.5f * v * (1.f + erff(v * 0.70710678118654752f)); // exact gelu
                    ((bf16_t*)Cout)[(size_t)gm * ldc + gn] = (bf16_t)a;
                } else {
                    ((float*)Cout)[(size_t)gm * ldc + gn] = v;
                }
            }
        }
    }
}

// ---------------- A = K^T Q partials per (b,h), 8 token chunks ----------------
// qkvg layout: [(b*1024+n)*4096 + s*1024 + h*64 + e], s in {q,k,v,g}
__global__ __launch_bounds__(256) void attn_A(const bf16_t* __restrict__ qkvg,
                                              float* __restrict__ Apart) {
    const int bh = blockIdx.x;           // 0..31
    const int p = blockIdx.y;            // 0..7
    const int b = bh >> 4, h = bh & 15;
    const int tid = threadIdx.x;
    __shared__ float ks[32][64];
    __shared__ float qs[32][64];
    float acc[4][4] = {};
    const int dg = tid >> 4, eg = tid & 15;
    const int stok = tid >> 3, se0 = (tid & 7) * 8;
    const size_t base = ((size_t)b * 1024) * 4096 + (size_t)h * 64;

    for (int t0 = p * 128; t0 < p * 128 + 128; t0 += 32) {
        __syncthreads();
        size_t rowb = base + (size_t)(t0 + stok) * 4096;
        bf16x8 qv8 = *(const bf16x8*)(&qkvg[rowb + se0]);
        bf16x8 kv8 = *(const bf16x8*)(&qkvg[rowb + 1024 + se0]);
#pragma unroll
        for (int jj = 0; jj < 8; ++jj) {
            qs[stok][se0 + jj] = (float)qv8[jj];
            ks[stok][se0 + jj] = (float)kv8[jj];
        }
        __syncthreads();
#pragma unroll 8
        for (int tt = 0; tt < 32; ++tt) {
            f32x4 kv = *(const f32x4*)(&ks[tt][dg * 4]);
            f32x4 qv = *(const f32x4*)(&qs[tt][eg * 4]);
#pragma unroll
            for (int i = 0; i < 4; ++i)
#pragma unroll
                for (int j = 0; j < 4; ++j) acc[i][j] += kv[i] * qv[j];
        }
    }
    float* dst = Apart + ((size_t)p * 32 + bh) * 4096;
#pragma unroll
    for (int i = 0; i < 4; ++i)
#pragma unroll
        for (int j = 0; j < 4; ++j)
            dst[(dg * 4 + i) * 64 + eg * 4 + j] = acc[i][j];
}

// ---------------- reduce partials -> A, compute z ----------------
__global__ __launch_bounds__(256) void reduce_A_z(const float* __restrict__ Apart,
                                                  float* __restrict__ A,
                                                  float* __restrict__ z) {
    const int bh = blockIdx.x;
    const int tid = threadIdx.x;
    __shared__ float As[4096];
    for (int i0 = tid * 4; i0 < 4096; i0 += 1024) {
        f32x4 s = {};
#pragma unroll
        for (int p = 0; p < 8; ++p) {
            f32x4 v = *(const f32x4*)(&Apart[((size_t)p * 32 + bh) * 4096 + i0]);
            s += v;
        }
        *(f32x4*)(&As[i0]) = s;
        *(f32x4*)(&A[(size_t)bh * 4096 + i0]) = s;
    }
    __syncthreads();
    if (tid < 64) {
        float s = 0.f;
#pragma unroll 8
        for (int d = 0; d < 64; ++d) s += As[d * 64 + tid];
        z[bh * 64 + tid] = 1.0f / (s * 0.125f + 1024.0f);
    }
}

// ---------------- Y = ((SCALE*V@A + V) * z * g), scrambled-reshaped, bf16 ----------------
__global__ __launch_bounds__(256) void out_Y(const bf16_t* __restrict__ qkvg,
                                             const float* __restrict__ A,
                                             const float* __restrict__ z,
                                             bf16_t* __restrict__ Y) {
    const int bh = blockIdx.x;
    const int b = bh >> 4, h = bh & 15;
    const int chunk = blockIdx.y;        // 0..15 -> 64 tokens
    const int tid = threadIdx.x;
    __shared__ float As[64][64];         // A[d][e]
    __shared__ float vs[32][64];
    __shared__ float zs[64];
    for (int i = tid; i < 4096; i += 256) As[i >> 6][i & 63] = A[(size_t)bh * 4096 + i];
    if (tid < 64) zs[tid] = z[bh * 64 + tid];
    const size_t base = ((size_t)b * 1024) * 4096 + (size_t)h * 64;
    const int e = tid & 63, trow = tid >> 6;
    const int stok = tid >> 3, se0 = (tid & 7) * 8;

    for (int t0 = chunk * 64; t0 < chunk * 64 + 64; t0 += 32) {
        __syncthreads();
        bf16x8 vv8 = *(const bf16x8*)(&qkvg[base + (size_t)(t0 + stok) * 4096 + 2048 + se0]);
#pragma unroll
        for (int jj = 0; jj < 8; ++jj) vs[stok][se0 + jj] = (float)vv8[jj];
        __syncthreads();
#pragma unroll
        for (int kk = 0; kk < 8; ++kk) {
            int ml = trow * 8 + kk;
            int m = t0 + ml;
            float s = 0.f;
#pragma unroll 8
            for (int d = 0; d < 64; ++d) s += vs[ml][d] * As[d][e];
            float g = (float)qkvg[base + (size_t)m * 4096 + 3072 + e];
            float o = (s * 0.125f + vs[ml][e]) * zs[e] * g;
            Y[((size_t)b * 1024 + h * 64 + (m >> 4)) * 1024 + ((m & 15) << 6) + e] = (bf16_t)o;
        }
    }
}

extern "C" void kernel_launch(void* const* d_in, const int* in_sizes, int n_in,
                              void* d_out, int out_size, void* d_ws, size_t ws_size,
                              hipStream_t stream) {
    const float* x      = (const float*)d_in[0];
    const float* w_qkvg = (const float*)d_in[1];
    const float* b_qkvg = (const float*)d_in[2];
    const float* w_proj = (const float*)d_in[3];
    const float* b_proj = (const float*)d_in[4];

    char* p = (char*)d_ws;
    bf16_t* xb    = (bf16_t*)p; p += (size_t)2048 * 1024 * 2;
    bf16_t* w1b   = (bf16_t*)p; p += (size_t)4096 * 1024 * 2;
    bf16_t* w2b   = (bf16_t*)p; p += (size_t)1024 * 1024 * 2;
    bf16_t* qkvg  = (bf16_t*)p; p += (size_t)2048 * 4096 * 2;
    float*  Apart = (float*)p;  p += (size_t)8 * 32 * 4096 * 4;
    float*  Afull = (float*)p;  p += (size_t)32 * 4096 * 4;
    float*  zbuf  = (float*)p;  p += (size_t)32 * 64 * 4;
    bf16_t* Ybuf  = (bf16_t*)p; p += (size_t)2048 * 1024 * 2;

    // quad counts: x 524288, w_qkvg 1048576, w_proj 262144 -> 7168 blocks
    cvt3<<<7168, 256, 0, stream>>>(x, xb, 524288, w_qkvg, w1b, 1048576, w_proj, w2b, 262144);

    // GEMM1 as 4 sub-GEMMs of the proven fast shape (2048x1024x1024, 64x64, 512 blocks):
    // section s uses weights w1b + s*1024*1024, bias b_qkvg + s*1024, writes qkvg cols [s*1024, ...)
    gemm_bt<64, 64, 2, 2, 0><<<512, 256, 0, stream>>>(xb, w1b + (size_t)0 * 1024 * 1024,
        b_qkvg + 0 * 1024, (void*)(qkvg + 0 * 1024), 2048, 1024, 1024, 4096);   // q softplus
    gemm_bt<64, 64, 2, 2, 0><<<512, 256, 0, stream>>>(xb, w1b + (size_t)1 * 1024 * 1024,
        b_qkvg + 1 * 1024, (void*)(qkvg + 1 * 1024), 2048, 1024, 1024, 4096);   // k softplus
    gemm_bt<64, 64, 2, 2, 1><<<512, 256, 0, stream>>>(xb, w1b + (size_t)2 * 1024 * 1024,
        b_qkvg + 2 * 1024, (void*)(qkvg + 2 * 1024), 2048, 1024, 1024, 4096);   // v gelu
    gemm_bt<64, 64, 2, 2, 1><<<512, 256, 0, stream>>>(xb, w1b + (size_t)3 * 1024 * 1024,
        b_qkvg + 3 * 1024, (void*)(qkvg + 3 * 1024), 2048, 1024, 1024, 4096);   // g gelu

    attn_A<<<dim3(32, 8), 256, 0, stream>>>(qkvg, Apart);
    reduce_A_z<<<32, 256, 0, stream>>>(Apart, Afull, zbuf);
    out_Y<<<dim3(32, 16), 256, 0, stream>>>(qkvg, Afull, zbuf, Ybuf);
    // GEMM2: 2048x1024x1024, 64x64 tiles -> 512 blocks (unchanged proven config)
    gemm_bt<64, 64, 2, 2, 2><<<512, 256, 0, stream>>>(Ybuf, w2b, b_proj, d_out, 2048, 1024, 1024, 1024);
}

// Round 8
// 106.317 us; speedup vs baseline: 1.4594x; 1.2353x over previous
//
#include <hip/hip_runtime.h>
#include <hip/hip_bf16.h>
#include <math.h>

typedef float f32x4 __attribute__((ext_vector_type(4)));
typedef __bf16 bf16_t;
typedef bf16_t bf16x8 __attribute__((ext_vector_type(8)));
typedef bf16_t bf16x4 __attribute__((ext_vector_type(4)));

// async global->LDS, 16B per lane; LDS dest = wave-uniform base + lane*16
__device__ __forceinline__ void gload_lds16(const bf16_t* g, bf16_t* l) {
    __builtin_amdgcn_global_load_lds(
        (const __attribute__((address_space(1))) unsigned int*)g,
        (__attribute__((address_space(3))) unsigned int*)l, 16, 0, 0);
}

template<int N_IMM>
__device__ __forceinline__ void wait_vmcnt() {
    if constexpr (N_IMM == 0) asm volatile("s_waitcnt vmcnt(0)" ::: "memory");
    else if constexpr (N_IMM == 2) asm volatile("s_waitcnt vmcnt(2)" ::: "memory");
    else if constexpr (N_IMM == 3) asm volatile("s_waitcnt vmcnt(3)" ::: "memory");
    else if constexpr (N_IMM == 4) asm volatile("s_waitcnt vmcnt(4)" ::: "memory");
    else static_assert(N_IMM == 0, "unsupported vmcnt");
}

// ---------------- fused fp32 -> bf16 conversion for 3 arrays ----------------
__global__ __launch_bounds__(256) void cvt3(const float* __restrict__ a, bf16_t* __restrict__ ao, int na4,
                                            const float* __restrict__ b, bf16_t* __restrict__ bo, int nb4,
                                            const float* __restrict__ c, bf16_t* __restrict__ co, int nc4) {
    int q = blockIdx.x * 256 + threadIdx.x;   // quad index
    const float* src; bf16_t* dst;
    if (q < na4)            { src = a + (size_t)q * 4;              dst = ao + (size_t)q * 4; }
    else if (q < na4 + nb4) { int r = q - na4; src = b + (size_t)r * 4; dst = bo + (size_t)r * 4; }
    else if (q < na4 + nb4 + nc4) { int r = q - na4 - nb4; src = c + (size_t)r * 4; dst = co + (size_t)r * 4; }
    else return;
    float4 v = *reinterpret_cast<const float4*>(src);
    bf16x4 o;
    o[0] = (bf16_t)v.x; o[1] = (bf16_t)v.y; o[2] = (bf16_t)v.z; o[3] = (bf16_t)v.w;
    *reinterpret_cast<bf16x4*>(dst) = o;
}

// ---------------- bf16 GEMM: C = A @ B^T (+bias, epilogue) ----------------
// STATIC triple-buffer ring, K-loop unrolled x3 (+2-phase tail), K=1024 fixed.
// Named __shared__ buffers let the compiler statically disambiguate the async
// global_load_lds writes (buffer t+2) from the ds_reads (buffer t) -> no
// conservative vmcnt serialization. One raw barrier per phase; stage issued
// AFTER the barrier into the buffer whose reads finished a phase ago.
// Depth-2 prefetch, counted vmcnt(LOADS).
// Staging linear LDS, source-preswizzled (ch = pos ^ ((row>>1)&3));
// swizzled ds_read_b128 -> 0 bank conflicts (verified R2).
// Bijective XCD chunk swizzle (verified R4: FETCH ideal).
// EPI 0: qkvg epilogue (softplus / gelu by col>>10), bf16. EPI 1: +bias, fp32.
template<int BM, int BN, int MR, int NR, int EPI>
__global__ __launch_bounds__(256) void gemm_bt(const bf16_t* __restrict__ A,
                                               const bf16_t* __restrict__ B,
                                               const float* __restrict__ bias,
                                               void* __restrict__ Cout,
                                               int M, int N) {
    constexpr int K = 1024;
    constexpr int TNUM = K / 32;                    // 32 K-tiles
    constexpr int WCOLS = BN / (NR * 16);
    constexpr int WROWS = BM / (MR * 16);
    static_assert(WROWS * WCOLS == 4, "4 waves");
    constexpr int ASEG = BM / 64, BSEG = BN / 64;   // staging instrs per thread
    constexpr int LOADS = ASEG + BSEG;

    __shared__ __align__(16) bf16_t Sa0[BM * 32];
    __shared__ __align__(16) bf16_t Sb0[BN * 32];
    __shared__ __align__(16) bf16_t Sa1[BM * 32];
    __shared__ __align__(16) bf16_t Sb1[BN * 32];
    __shared__ __align__(16) bf16_t Sa2[BM * 32];
    __shared__ __align__(16) bf16_t Sb2[BN * 32];

    const int tid = threadIdx.x;
    const int lane = tid & 63;
    const int w = tid >> 6;
    const int wr = w / WCOLS, wc = w % WCOLS;

    // bijective XCD swizzle: 8 chunks of 8 x chunkN tiles (~4MB per XCD)
    const int NTM = M / BM, NTN = N / BN;
    const int CHM = NTM >> 3;
    const int chunkN = (NTN * CHM) >> 3;
    const int c = blockIdx.x & 7;
    const int pp = blockIdx.x >> 3;
    const int mt = (c % CHM) * 8 + (pp & 7);
    const int nt = (c / CHM) * chunkN + (pp >> 3);
    const int m0 = mt * BM, n0 = nt * BN;

    const int l15 = lane & 15, lg = lane >> 4;
    const int srow = lane >> 2, pos = lane & 3;

    f32x4 acc[MR][NR] = {};

    auto stageTo = [&](bf16_t* Ad, bf16_t* Bd, int k0) {
#pragma unroll
        for (int t = 0; t < ASEG; ++t) {
            int s = w + t * 4;
            int row = s * 16 + srow;
            int ch = pos ^ ((row >> 1) & 3);
            gload_lds16(&A[(size_t)(m0 + row) * K + k0 + ch * 8], &Ad[s * 512]);
        }
#pragma unroll
        for (int t = 0; t < BSEG; ++t) {
            int s = w + t * 4;
            int row = s * 16 + srow;
            int ch = pos ^ ((row >> 1) & 3);
            gload_lds16(&B[(size_t)(n0 + row) * K + k0 + ch * 8], &Bd[s * 512]);
        }
    };

    auto compute = [&](const bf16_t* Ac, const bf16_t* Bc) {
        bf16x8 af[MR], bfr[NR];
#pragma unroll
        for (int i = 0; i < MR; ++i) {
            int ar = wr * MR * 16 + i * 16 + l15;
            af[i] = *(const bf16x8*)(&Ac[ar * 32 + (lg ^ ((ar >> 1) & 3)) * 8]);
        }
#pragma unroll
        for (int j = 0; j < NR; ++j) {
            int br = wc * NR * 16 + j * 16 + l15;
            bfr[j] = *(const bf16x8*)(&Bc[br * 32 + (lg ^ ((br >> 1) & 3)) * 8]);
        }
#pragma unroll
        for (int i = 0; i < MR; ++i)
#pragma unroll
            for (int j = 0; j < NR; ++j)
                acc[i][j] = __builtin_amdgcn_mfma_f32_16x16x32_bf16(af[i], bfr[j], acc[i][j], 0, 0, 0);
    };

    // prologue: tiles 0 -> P0, 1 -> P1
    stageTo(Sa0, Sb0, 0);
    stageTo(Sa1, Sb1, 32);

    // main: 10 x unroll-3, tiles 0..29; each phase stages tile t+2 two buffers ahead
    for (int t = 0; t < TNUM - 2; t += 3) {
        wait_vmcnt<LOADS>();
        __builtin_amdgcn_s_barrier();
        __builtin_amdgcn_sched_barrier(0);
        stageTo(Sa2, Sb2, (t + 2) * 32);
        compute(Sa0, Sb0);
        __builtin_amdgcn_sched_barrier(0);

        wait_vmcnt<LOADS>();
        __builtin_amdgcn_s_barrier();
        __builtin_amdgcn_sched_barrier(0);
        stageTo(Sa0, Sb0, (t + 3) * 32);
        compute(Sa1, Sb1);
        __builtin_amdgcn_sched_barrier(0);

        wait_vmcnt<LOADS>();
        __builtin_amdgcn_s_barrier();
        __builtin_amdgcn_sched_barrier(0);
        stageTo(Sa1, Sb1, (t + 4) * 32);
        compute(Sa2, Sb2);
        __builtin_amdgcn_sched_barrier(0);
    }
    // tail: tile 30 (P0), tile 31 (P1)
    wait_vmcnt<LOADS>();
    __builtin_amdgcn_s_barrier();
    __builtin_amdgcn_sched_barrier(0);
    compute(Sa0, Sb0);
    __builtin_amdgcn_sched_barrier(0);

    wait_vmcnt<0>();
    __builtin_amdgcn_s_barrier();
    __builtin_amdgcn_sched_barrier(0);
    compute(Sa1, Sb1);

    // epilogue: C/D layout col = lane&15, row = (lane>>4)*4 + reg
#pragma unroll
    for (int i = 0; i < MR; ++i) {
        int gm_base = m0 + wr * MR * 16 + i * 16 + lg * 4;
#pragma unroll
        for (int j = 0; j < NR; ++j) {
            int gn = n0 + wc * NR * 16 + j * 16 + l15;
            float bv = bias[gn];
#pragma unroll
            for (int r = 0; r < 4; ++r) {
                int gm = gm_base + r;
                float v = acc[i][j][r] + bv;
                if (EPI == 0) {
                    float a;
                    if ((gn >> 10) < 2) {
                        a = fmaxf(v, 0.f) + log1pf(expf(-fabsf(v)));           // softplus
                    } else {
                        a = 0.5f * v * (1.f + erff(v * 0.70710678118654752f)); // exact gelu
                    }
                    ((bf16_t*)Cout)[(size_t)gm * N + gn] = (bf16_t)a;
                } else {
                    ((float*)Cout)[(size_t)gm * N + gn] = v;
                }
            }
        }
    }
}

// ---------------- A = K^T Q partials per (b,h), 8 token chunks ----------------
// qkvg layout: [(b*1024+n)*4096 + s*1024 + h*64 + e], s in {q,k,v,g}
__global__ __launch_bounds__(256) void attn_A(const bf16_t* __restrict__ qkvg,
                                              float* __restrict__ Apart) {
    const int bh = blockIdx.x;           // 0..31
    const int p = blockIdx.y;            // 0..7
    const int b = bh >> 4, h = bh & 15;
    const int tid = threadIdx.x;
    __shared__ float ks[32][64];
    __shared__ float qs[32][64];
    float acc[4][4] = {};
    const int dg = tid >> 4, eg = tid & 15;
    const int stok = tid >> 3, se0 = (tid & 7) * 8;
    const size_t base = ((size_t)b * 1024) * 4096 + (size_t)h * 64;

    for (int t0 = p * 128; t0 < p * 128 + 128; t0 += 32) {
        __syncthreads();
        size_t rowb = base + (size_t)(t0 + stok) * 4096;
        bf16x8 qv8 = *(const bf16x8*)(&qkvg[rowb + se0]);
        bf16x8 kv8 = *(const bf16x8*)(&qkvg[rowb + 1024 + se0]);
#pragma unroll
        for (int jj = 0; jj < 8; ++jj) {
            qs[stok][se0 + jj] = (float)qv8[jj];
            ks[stok][se0 + jj] = (float)kv8[jj];
        }
        __syncthreads();
#pragma unroll 8
        for (int tt = 0; tt < 32; ++tt) {
            f32x4 kv = *(const f32x4*)(&ks[tt][dg * 4]);
            f32x4 qv = *(const f32x4*)(&qs[tt][eg * 4]);
#pragma unroll
            for (int i = 0; i < 4; ++i)
#pragma unroll
                for (int j = 0; j < 4; ++j) acc[i][j] += kv[i] * qv[j];
        }
    }
    float* dst = Apart + ((size_t)p * 32 + bh) * 4096;
#pragma unroll
    for (int i = 0; i < 4; ++i)
#pragma unroll
        for (int j = 0; j < 4; ++j)
            dst[(dg * 4 + i) * 64 + eg * 4 + j] = acc[i][j];
}

// ---------------- reduce partials -> A, compute z ----------------
__global__ __launch_bounds__(256) void reduce_A_z(const float* __restrict__ Apart,
                                                  float* __restrict__ A,
                                                  float* __restrict__ z) {
    const int bh = blockIdx.x;
    const int tid = threadIdx.x;
    __shared__ float As[4096];
    for (int i0 = tid * 4; i0 < 4096; i0 += 1024) {
        f32x4 s = {};
#pragma unroll
        for (int p = 0; p < 8; ++p) {
            f32x4 v = *(const f32x4*)(&Apart[((size_t)p * 32 + bh) * 4096 + i0]);
            s += v;
        }
        *(f32x4*)(&As[i0]) = s;
        *(f32x4*)(&A[(size_t)bh * 4096 + i0]) = s;
    }
    __syncthreads();
    if (tid < 64) {
        float s = 0.f;
#pragma unroll 8
        for (int d = 0; d < 64; ++d) s += As[d * 64 + tid];
        z[bh * 64 + tid] = 1.0f / (s * 0.125f + 1024.0f);
    }
}

// ---------------- Y = ((SCALE*V@A + V) * z * g), scrambled-reshaped, bf16 ----------------
__global__ __launch_bounds__(256) void out_Y(const bf16_t* __restrict__ qkvg,
                                             const float* __restrict__ A,
                                             const float* __restrict__ z,
                                             bf16_t* __restrict__ Y) {
    const int bh = blockIdx.x;
    const int b = bh >> 4, h = bh & 15;
    const int chunk = blockIdx.y;        // 0..15 -> 64 tokens
    const int tid = threadIdx.x;
    __shared__ float As[64][64];         // A[d][e]
    __shared__ float vs[32][64];
    __shared__ float zs[64];
    for (int i = tid; i < 4096; i += 256) As[i >> 6][i & 63] = A[(size_t)bh * 4096 + i];
    if (tid < 64) zs[tid] = z[bh * 64 + tid];
    const size_t base = ((size_t)b * 1024) * 4096 + (size_t)h * 64;
    const int e = tid & 63, trow = tid >> 6;
    const int stok = tid >> 3, se0 = (tid & 7) * 8;

    for (int t0 = chunk * 64; t0 < chunk * 64 + 64; t0 += 32) {
        __syncthreads();
        bf16x8 vv8 = *(const bf16x8*)(&qkvg[base + (size_t)(t0 + stok) * 4096 + 2048 + se0]);
#pragma unroll
        for (int jj = 0; jj < 8; ++jj) vs[stok][se0 + jj] = (float)vv8[jj];
        __syncthreads();
#pragma unroll
        for (int kk = 0; kk < 8; ++kk) {
            int ml = trow * 8 + kk;
            int m = t0 + ml;
            float s = 0.f;
#pragma unroll 8
            for (int d = 0; d < 64; ++d) s += vs[ml][d] * As[d][e];
            float g = (float)qkvg[base + (size_t)m * 4096 + 3072 + e];
            float o = (s * 0.125f + vs[ml][e]) * zs[e] * g;
            Y[((size_t)b * 1024 + h * 64 + (m >> 4)) * 1024 + ((m & 15) << 6) + e] = (bf16_t)o;
        }
    }
}

extern "C" void kernel_launch(void* const* d_in, const int* in_sizes, int n_in,
                              void* d_out, int out_size, void* d_ws, size_t ws_size,
                              hipStream_t stream) {
    const float* x      = (const float*)d_in[0];
    const float* w_qkvg = (const float*)d_in[1];
    const float* b_qkvg = (const float*)d_in[2];
    const float* w_proj = (const float*)d_in[3];
    const float* b_proj = (const float*)d_in[4];

    char* p = (char*)d_ws;
    bf16_t* xb    = (bf16_t*)p; p += (size_t)2048 * 1024 * 2;
    bf16_t* w1b   = (bf16_t*)p; p += (size_t)4096 * 1024 * 2;
    bf16_t* w2b   = (bf16_t*)p; p += (size_t)1024 * 1024 * 2;
    bf16_t* qkvg  = (bf16_t*)p; p += (size_t)2048 * 4096 * 2;
    float*  Apart = (float*)p;  p += (size_t)8 * 32 * 4096 * 4;
    float*  Afull = (float*)p;  p += (size_t)32 * 4096 * 4;
    float*  zbuf  = (float*)p;  p += (size_t)32 * 64 * 4;
    bf16_t* Ybuf  = (bf16_t*)p; p += (size_t)2048 * 1024 * 2;

    // quad counts: x 524288, w_qkvg 1048576, w_proj 262144 -> 7168 blocks
    cvt3<<<7168, 256, 0, stream>>>(x, xb, 524288, w_qkvg, w1b, 1048576, w_proj, w2b, 262144);

    // GEMM1: 2048x4096x1024, 128x64 tiles -> 1024 blocks (4/CU, 36KB LDS)
    gemm_bt<128, 64, 4, 2, 0><<<1024, 256, 0, stream>>>(xb, w1b, b_qkvg, (void*)qkvg, 2048, 4096);
    attn_A<<<dim3(32, 8), 256, 0, stream>>>(qkvg, Apart);
    reduce_A_z<<<32, 256, 0, stream>>>(Apart, Afull, zbuf);
    out_Y<<<dim3(32, 16), 256, 0, stream>>>(qkvg, Afull, zbuf, Ybuf);
    // GEMM2: 2048x1024x1024, 64x64 tiles -> 512 blocks (24KB LDS)
    gemm_bt<64, 64, 2, 2, 1><<<512, 256, 0, stream>>>(Ybuf, w2b, b_proj, d_out, 2048, 1024);
}